// Round 5
// baseline (324.183 us; speedup 1.0000x reference)
//
#include <hip/hip_runtime.h>

#define DD 256
#define BB 512

// workspace layout (float offsets)
#define OFF_RS   0          // 512*256 row sums
#define OFF_CSP  131072     // 2048*256 col-sum partials (4 per batch)
#define OFF_HFC  655360     // 4 fc1 pre-activations
#define OFF_PAR  655368     // bp[10] breakpoints
#define OFF_DE   655384     // 9 taps * (D,E): linear part coefficients
#define OFF_G    655408     // (kc*10+c)*4 + dr : G = |w1_c|*w2[c,dr,kc] (slot 3 unused)

typedef float v2f __attribute__((ext_vector_type(2)));

__device__ __forceinline__ v2f mk2(float a, float b) { v2f r; r.x = a; r.y = b; return r; }

__device__ __forceinline__ v2f fma2(v2f a, v2f b, v2f c) {
#if __has_builtin(__builtin_elementwise_fma)
  return __builtin_elementwise_fma(a, b, c);   // -> v_pk_fma_f32
#else
  return mk2(fmaf(a.x, b.x, c.x), fmaf(a.y, b.y, c.y));
#endif
}

__device__ __forceinline__ v2f max2z(v2f a) {
#if __has_builtin(__builtin_elementwise_max)
  return __builtin_elementwise_max(a, mk2(0.f, 0.f));
#else
  return mk2(fmaxf(a.x, 0.f), fmaxf(a.y, 0.f));
#endif
}

__device__ __forceinline__ float wave_red(float v) {
#pragma unroll
  for (int off = 32; off > 0; off >>= 1) v += __shfl_down(v, off, 64);
  return v;
}

// ---- K1: row sums + col-sum partials; block 2048 builds relu-decomp consts ----
__global__ __launch_bounds__(256) void sum_kernel(const float* __restrict__ x,
                                                  const float* __restrict__ w1,
                                                  const float* __restrict__ b1,
                                                  const float* __restrict__ w2,
                                                  float* __restrict__ ws) {
  const int bq = blockIdx.x;
  const int tid = threadIdx.x;
  if (bq == 2048) {                  // ---- const-builder block ----
    const int t = tid;
    float w1v[10], b1v[10];
#pragma unroll
    for (int c = 0; c < 10; ++c) { w1v[c] = w1[c]; b1v[c] = b1[c]; }
    // exact decomposition: relu(w1*e+b1) = |w1|*relu(e-bp) + [w1<0]*(w1*e+b1)
    //                      (w1==0: const relu(b1))
    if (t < 10) ws[OFF_PAR + t] = (w1v[t] != 0.f) ? (-b1v[t] / w1v[t]) : 0.f;
    if (t < 9) {                     // D,E per tap tt = dr*3+kc
      float D = 0.f, E = 0.f;
      for (int c = 0; c < 10; ++c) {
        if (w1v[c] < 0.f) { D += w1v[c] * w2[c * 9 + t]; E += b1v[c] * w2[c * 9 + t]; }
        else if (w1v[c] == 0.f && b1v[c] > 0.f) { E += b1v[c] * w2[c * 9 + t]; }
      }
      ws[OFF_DE + t * 2] = D;
      ws[OFF_DE + t * 2 + 1] = E;
    }
    if (t < 90) {                    // G[c][tt] = |w1_c| * w2[c,tt]
      const int c = t / 9, tt = t % 9;
      const int dr = tt / 3, kc = tt % 3;
      ws[OFF_G + (kc * 10 + c) * 4 + dr] = fabsf(w1v[c]) * w2[c * 9 + tt];
    }
    return;
  }
  // ---- streaming sum block (unchanged, proven) ----
  const int b = bq >> 2;
  const int q = bq & 3;
  const int lane = tid & 63;
  const int wv = tid >> 6;
  __shared__ float rowp[64][65];
  __shared__ float csl[4][DD];
  __shared__ float segp[4][64];
  float4 cacc = make_float4(0.f, 0.f, 0.f, 0.f);
  const float4* px = (const float4*)(x + ((size_t)b << 16) + ((size_t)(q * 64 + wv * 16) << 8));
#pragma unroll
  for (int r = 0; r < 16; ++r) {
    float4 val = px[r * 64 + lane];
    cacc.x += val.x; cacc.y += val.y; cacc.z += val.z; cacc.w += val.w;
    rowp[wv * 16 + r][lane] = (val.x + val.y) + (val.z + val.w);
  }
  ((float4*)csl[wv])[lane] = cacc;
  __syncthreads();
  {
    const int row = tid & 63, seg = tid >> 6;
    const float* rp = rowp[row] + seg * 16;
    float s = 0.f;
#pragma unroll
    for (int k = 0; k < 16; ++k) s += rp[k];
    segp[seg][row] = s;
  }
  __syncthreads();
  if (tid < 64)
    ws[OFF_RS + b * DD + q * 64 + tid] =
        (segp[0][tid] + segp[1][tid]) + (segp[2][tid] + segp[3][tid]);
  ws[OFF_CSP + bq * DD + tid] =
      (csl[0][tid] + csl[1][tid]) + (csl[2][tid] + csl[3][tid]);
  if (bq == 0 && tid < 4) ws[OFF_HFC + tid] = 0.f;
}

// ---- K2: 4 blocks/image x 4 waves; branch-free all-VALU relu-sum taps ----
__global__ __launch_bounds__(256, 2) void conv_kernel(const float* __restrict__ b2p,
                                                      const float* __restrict__ fc1w,
                                                      float* __restrict__ ws) {
  const int b = blockIdx.x >> 2;     // image
  const int h = blockIdx.x & 3;      // quarter (run group)
  const int tid = threadIdx.x;
  const int w = tid >> 6;            // wave 0..3
  const int lane = tid & 63;
  const int run = (h << 2) | w;      // 0..15 in the balanced run map

  int wb, r0, r1;
  switch (run) {
    case 0:  wb = 0; r0 = 0;   r1 = 43;  break;
    case 1:  wb = 0; r0 = 43;  r1 = 86;  break;
    case 2:  wb = 0; r0 = 86;  r1 = 129; break;
    case 3:  wb = 0; r0 = 129; r1 = 172; break;
    case 4:  wb = 0; r0 = 172; r1 = 214; break;
    case 5:  wb = 0; r0 = 214; r1 = 256; break;
    case 6:  wb = 1; r0 = 62;  r1 = 101; break;
    case 7:  wb = 1; r0 = 101; r1 = 140; break;
    case 8:  wb = 1; r0 = 140; r1 = 179; break;
    case 9:  wb = 1; r0 = 179; r1 = 218; break;
    case 10: wb = 1; r0 = 218; r1 = 256; break;
    case 11: wb = 2; r0 = 126; r1 = 170; break;
    case 12: wb = 2; r0 = 170; r1 = 213; break;
    case 13: wb = 2; r0 = 213; r1 = 256; break;
    case 14: wb = 3; r0 = 190; r1 = 223; break;
    default: wb = 3; r0 = 223; r1 = 256; break;
  }
  const int jmin = wb * 64;
  const int j = jmin + lane;
  const int dlim = jmin + 63;        // last input row with any masked lane

  __shared__ float rs_s[DD];
  __shared__ float cs_s[DD];
  __shared__ __align__(16) float wkA[DD][4];
  __shared__ float segsum_s[4][4];
  __shared__ float red_s[16];

  // ---- wave-uniform constants (scalar-load friendly, loop-invariant) ----
  float bp_r[10];
  v2f Gp[3][10];                     // (G_dr0, G_dr1) per (kc, c)
  float G2[3][10];                   // G_dr2 per (kc, c)
  v2f Dp[3], Ep[3];
  float D2[3], E2[3];
#pragma unroll
  for (int c = 0; c < 10; ++c) bp_r[c] = ws[OFF_PAR + c];
#pragma unroll
  for (int kc = 0; kc < 3; ++kc) {
#pragma unroll
    for (int c = 0; c < 10; ++c) {
      const float* gp = ws + OFF_G + (kc * 10 + c) * 4;
      Gp[kc][c] = mk2(gp[0], gp[1]);
      G2[kc][c] = gp[2];
    }
    Dp[kc] = mk2(ws[OFF_DE + kc * 2], ws[OFF_DE + (3 + kc) * 2]);
    Ep[kc] = mk2(ws[OFF_DE + kc * 2 + 1], ws[OFF_DE + (3 + kc) * 2 + 1]);
    D2[kc] = ws[OFF_DE + (6 + kc) * 2];
    E2[kc] = ws[OFF_DE + (6 + kc) * 2 + 1];
  }

  // ---- preamble ----
  {
    rs_s[tid] = ws[OFF_RS + b * DD + tid];
    const float* csp = ws + OFF_CSP + (b * 4) * DD + tid;
    cs_s[tid] = (csp[0] + csp[DD]) + (csp[2 * DD] + csp[3 * DD]);
#pragma unroll
    for (int k = 0; k < 4; ++k) wkA[tid][k] = fc1w[k * (BB * DD) + b * DD + tid];
  }
  __syncthreads();
  if (tid < 16) {
    const int ss = tid >> 2, k = tid & 3;
    float s = 0.f;
#pragma unroll
    for (int r = 0; r < 64; ++r) s += wkA[ss * 64 + r][k];
    segsum_s[ss][k] = s;
  }
  __syncthreads();

  const float b2v = b2p[0];
  const float yb = fmaxf(b2v, 0.f);

  float csr[3], vf[3];
  csr[0] = (j >= 1) ? cs_s[j - 1] : 0.f;
  csr[1] = cs_s[j];
  csr[2] = (j < DD - 1) ? cs_s[j + 1] : 0.f;
  vf[0] = (j >= 1) ? 1.f : 0.f;
  vf[1] = 1.f;
  vf[2] = (j < DD - 1) ? 1.f : 0.f;
  v2f vf2[3];
#pragma unroll
  for (int kc = 0; kc < 3; ++kc) vf2[kc] = mk2(vf[kc], vf[kc]);

  // fast-path shifted constants: boundary taps -> e-BIG so relu terms vanish
  const float csrF0 = (j >= 1) ? csr[0] : -1e30f;
  const float csrF2 = (j < DD - 1) ? csr[2] : -1e30f;
  v2f cm02[10]; float cm1[10];
#pragma unroll
  for (int c = 0; c < 10; ++c) {
    cm02[c] = mk2(csrF0 - bp_r[c], csrF2 - bp_r[c]);
    cm1[c] = csr[1] - bp_r[c];
  }

  // per-lane fold of the unconditional linear (D,E) part
  v2f al01 = mk2(0.f, 0.f), be01 = mk2(0.f, 0.f);
  float al2 = 0.f, be2 = 0.f;
#pragma unroll
  for (int kc = 0; kc < 3; ++kc) {
    al01 = fma2(vf2[kc], Dp[kc], al01);
    be01 = fma2(vf2[kc], fma2(Dp[kc], mk2(csr[kc], csr[kc]), Ep[kc]), be01);
    al2 = fmaf(vf[kc], D2[kc], al2);
    be2 = fmaf(vf[kc], fmaf(D2[kc], csr[kc], E2[kc]), be2);
  }

  const int iend = (r1 == DD) ? DD - 1 : r1;
  float P = 0.f, Q = 0.f;
  float vcol = 0.f;
  v2f a01 = mk2(0.f, 0.f);
  v2f a23 = mk2(0.f, 0.f);

  // fast eval: all taps in-tril; pure-VALU relu-sum (no LDS gather)
  auto fast_eval = [&](float rsv, v2f& R01, float& R2) {
    const v2f rv2 = mk2(rsv, rsv);
    v2f S0 = mk2(0.f, 0.f), S1 = mk2(0.f, 0.f), S2 = mk2(0.f, 0.f);
    float T0 = 0.f, T1 = 0.f, T2 = 0.f;
#pragma unroll
    for (int c = 0; c < 10; ++c) {
      const v2f u02 = max2z(rv2 + cm02[c]);        // (u_kc0, u_kc2)
      const float u1 = fmaxf(rsv + cm1[c], 0.f);
      S0 = fma2(mk2(u02.x, u02.x), Gp[0][c], S0);
      S1 = fma2(mk2(u1, u1),       Gp[1][c], S1);
      S2 = fma2(mk2(u02.y, u02.y), Gp[2][c], S2);
      T0 = fmaf(u02.x, G2[0][c], T0);
      T1 = fmaf(u1,    G2[1][c], T1);
      T2 = fmaf(u02.y, G2[2][c], T2);
    }
    R01 = fma2(al01, rv2, be01) + ((S0 + S1) + S2);
    R2  = fmaf(al2, rsv, be2) + ((T0 + T1) + T2);
  };

  // guarded eval: per-tap tril mask, same exact identity
  auto guard_eval = [&](float rsv, int i, v2f& R01, float& R2) {
#pragma unroll
    for (int kc = 0; kc < 3; ++kc) {
      const float e = rsv + csr[kc];
      const float m = ((j - 1 + kc) <= i) ? vf[kc] : 0.f;
      v2f t01 = fma2(Dp[kc], mk2(e, e), Ep[kc]);
      float t2 = fmaf(D2[kc], e, E2[kc]);
#pragma unroll
      for (int c = 0; c < 10; ++c) {
        const float u = fmaxf(e - bp_r[c], 0.f);
        t01 = fma2(mk2(u, u), Gp[kc][c], t01);
        t2 = fmaf(u, G2[kc][c], t2);
      }
      R01 = fma2(mk2(m, m), t01, R01);
      R2 = fmaf(m, t2, R2);
    }
  };

  auto finalize = [&](int i, float R2v) {
    const float yd = fmaxf(P + R2v + b2v, 0.f) - yb;
    vcol += yd;
    const float4 wkv = *(const float4*)wkA[i - 1];
    a01 = fma2(mk2(yd, yd), mk2(wkv.x, wkv.y), a01);
    a23 = fma2(mk2(yd, yd), mk2(wkv.z, wkv.w), a23);
  };

  if (r0 >= dlim + 2) {
    // ---- interior-class run: 2 fast warmups (no finalize), then fast loop ----
    for (int i = r0 - 1; i <= r0; ++i) {
      v2f R01; float R2;
      fast_eval(rs_s[i], R01, R2);
      P = Q + R01.y; Q = R01.x;
    }
    for (int i = r0 + 1; i <= iend; ++i) {
      v2f R01; float R2;
      fast_eval(rs_s[i], R01, R2);
      finalize(i, R2);
      P = Q + R01.y; Q = R01.x;
    }
  } else {
    // ---- diagonal-class run: guarded phase, then unmasked fast continuation ----
    const int ibeg = (r0 == 0) ? 0 : r0 - 1;
    const int ffrom = r0 + 1;
    const int gend = (iend < dlim) ? iend : dlim;
    for (int i = ibeg; i <= gend; ++i) {
      v2f R01 = mk2(0.f, 0.f); float R2 = 0.f;
      if (j - 1 <= i) guard_eval(rs_s[i], i, R01, R2);
      if (i >= ffrom) finalize(i, R2);
      P = Q + R01.y; Q = R01.x;
    }
    for (int i = dlim + 1; i <= iend; ++i) {
      v2f R01; float R2;
      fast_eval(rs_s[i], R01, R2);
      finalize(i, R2);
      P = Q + R01.y; Q = R01.x;
    }
  }
  if (r1 == DD) {                    // flush output row 255
    const float yd = fmaxf(P + b2v, 0.f) - yb;
    vcol += yd;
    const float4 wkv = *(const float4*)wkA[DD - 1];
    a01 = fma2(mk2(yd, yd), mk2(wkv.x, wkv.y), a01);
    a23 = fma2(mk2(yd, yd), mk2(wkv.z, wkv.w), a23);
  }

  // column-sum term: vcol * Wk[b, j]
  const float4 wkj = *(const float4*)wkA[j];
  a01 = fma2(mk2(vcol, vcol), mk2(wkj.x, wkj.y), a01);
  a23 = fma2(mk2(vcol, vcol), mk2(wkj.z, wkj.w), a23);

  float acc0 = wave_red(a01.x), acc1 = wave_red(a01.y);
  float acc2 = wave_red(a23.x), acc3 = wave_red(a23.y);
  if (lane == 0) {
    red_s[w * 4 + 0] = acc0; red_s[w * 4 + 1] = acc1;
    red_s[w * 4 + 2] = acc2; red_s[w * 4 + 3] = acc3;
  }
  __syncthreads();
  if (tid < 4) {
    float s = (red_s[0 * 4 + tid] + red_s[1 * 4 + tid]) +
              (red_s[2 * 4 + tid] + red_s[3 * 4 + tid]);
    // closed-form yb baseline, quarter per block: 128*yb*sum_r wk[r]
    const float wt = (segsum_s[0][tid] + segsum_s[1][tid]) +
                     (segsum_s[2][tid] + segsum_s[3][tid]);
    s = fmaf(128.f * yb, wt, s);
    atomicAdd(&ws[OFF_HFC + tid], s);
  }
}

// ---- K3: relu(fc1) -> fc2 -> 2 outputs ----
__global__ void fc_kernel(const float* __restrict__ fc1b, const float* __restrict__ fc2w,
                          const float* __restrict__ fc2b, const float* __restrict__ ws,
                          float* __restrict__ out) {
  if (threadIdx.x == 0 && blockIdx.x == 0) {
    float o0 = fc2b[0], o1 = fc2b[1];
#pragma unroll
    for (int k = 0; k < 4; ++k) {
      float h = fmaxf(ws[OFF_HFC + k] + fc1b[k], 0.f);
      o0 += fc2w[k] * h;
      o1 += fc2w[4 + k] * h;
    }
    out[0] = o0; out[1] = o1;
  }
}

extern "C" void kernel_launch(void* const* d_in, const int* in_sizes, int n_in,
                              void* d_out, int out_size, void* d_ws, size_t ws_size,
                              hipStream_t stream) {
  const float* x    = (const float*)d_in[0];
  const float* w1   = (const float*)d_in[1];
  const float* b1   = (const float*)d_in[2];
  const float* w2   = (const float*)d_in[3];
  const float* b2   = (const float*)d_in[4];
  const float* fc1w = (const float*)d_in[5];
  const float* fc1b = (const float*)d_in[6];
  const float* fc2w = (const float*)d_in[7];
  const float* fc2b = (const float*)d_in[8];
  float* out = (float*)d_out;
  float* ws  = (float*)d_ws;

  hipLaunchKernelGGL(sum_kernel,  dim3(2049), dim3(256), 0, stream, x, w1, b1, w2, ws);
  hipLaunchKernelGGL(conv_kernel, dim3(2048), dim3(256), 0, stream, b2, fc1w, ws);
  hipLaunchKernelGGL(fc_kernel,   dim3(1), dim3(64), 0, stream, fc1b, fc2w, fc2b, ws, out);
}